// Round 15
// baseline (104.751 us; speedup 1.0000x reference)
//
#include <hip/hip_runtime.h>
#include <hip/hip_bf16.h>
#include <cstdint>

#define NB 16
#define NC 512
#define NPIX 1024
#define NHEADS 4
#define NEMB 128

typedef short bf16x8 __attribute__((ext_vector_type(8)));
typedef float f32x4 __attribute__((ext_vector_type(4)));
typedef float f32x16 __attribute__((ext_vector_type(16)));
typedef unsigned short u16x4 __attribute__((ext_vector_type(4)));
typedef unsigned short u16x8 __attribute__((ext_vector_type(8)));

__device__ __forceinline__ unsigned short f2bf(float f) {
  union { float f; unsigned u; } c; c.f = f;
  return (unsigned short)((c.u + 0x7FFFu + ((c.u >> 16) & 1u)) >> 16);
}

__device__ __forceinline__ unsigned cvtpk_bf16(float lo, float hi) {
  unsigned r;
  asm("v_cvt_pk_bf16_f32 %0, %1, %2" : "=v"(r) : "v"(lo), "v"(hi));
  return r;
}

__device__ __forceinline__ void gload_lds16(const void* g, void* l) {
  __builtin_amdgcn_global_load_lds(
      (const __attribute__((address_space(1))) unsigned int*)g,
      (__attribute__((address_space(3))) unsigned int*)l, 16, 0, 0);
}

// ---------- merged prep: blocks 0..2047 transpose x -> xt; 2048..2303 convert w ----------
__global__ void k_prep(const float* __restrict__ x, unsigned short* __restrict__ xt,
                       const float* __restrict__ wq, const float* __restrict__ wk,
                       const float* __restrict__ wv, unsigned short* __restrict__ wb) {
  int bid = blockIdx.x;
  if (bid >= 2048) {
    int wbid = bid - 2048;
    for (int i = wbid * 256 + threadIdx.x; i < 3 * 65536; i += 256 * 256) {
      int p = i >> 16, idx = i & 65535;
      const float* src = p == 0 ? wq : (p == 1 ? wk : wv);
      float4 v = ((const float4*)src)[idx];
      u16x4 o = { f2bf(v.x), f2bf(v.y), f2bf(v.z), f2bf(v.w) };
      ((u16x4*)(wb + (size_t)p * NC * NC))[idx] = o;
    }
    return;
  }
  __shared__ float tile[4][32][33];
  int nt = bid & 31, ct4 = (bid >> 5) & 3, b = bid >> 7;
  int n0 = nt * 32, c0 = ct4 * 128;
  int t = threadIdx.x;
  int r = t >> 3, q = t & 7;
#pragma unroll
  for (int s = 0; s < 4; s++) {
    float4 v = *(const float4*)(x + ((size_t)(b * NC + c0 + s * 32 + r)) * NPIX + n0 + q * 4);
    tile[s][r][q * 4 + 0] = v.x; tile[s][r][q * 4 + 1] = v.y;
    tile[s][r][q * 4 + 2] = v.z; tile[s][r][q * 4 + 3] = v.w;
  }
  __syncthreads();
#pragma unroll
  for (int pass = 0; pass < 2; pass++) {
    int idx = pass * 256 + t;
    int n = idx >> 4;
    int c8 = (idx & 15) * 8;
    int s = c8 >> 5, cl = c8 & 31;
    u16x8 o;
#pragma unroll
    for (int j = 0; j < 8; j++) o[j] = f2bf(tile[s][cl + j][n]);
    *(u16x8*)(xt + ((size_t)(b * NPIX + n0 + n)) * NC + c0 + c8) = o;
  }
}

// ---------- QKV projection GEMM (LDS-restaged coalesced epilogue) ----------
// p==0: Q -> (acc+bias)*scale*log2e, [b][hd][n][e]  (exp2-domain)
// p==1: K -> acc+bias+rh+rw, tiles 16KB: elem(jl,e) at byte jl*256 + ((2e)^((jl&7)<<4))
// p==2: V -> acc+bias, FRAG-ORDER: elem(d,j) j=(jt*4+c2)*16+h5*8+j8 at
//            [pair][(jt*4+c2)*2+h5][d(128)][j8(8)]  (k_attn reads 1KB coalesced direct)
__global__ __launch_bounds__(256, 3) void k_qkv(
    const unsigned short* __restrict__ wb, const unsigned short* __restrict__ xt,
    const float* __restrict__ qb, const float* __restrict__ kb, const float* __restrict__ vb,
    const float* __restrict__ rh, const float* __restrict__ rw,
    unsigned short* __restrict__ Qs, unsigned short* __restrict__ Kn,
    unsigned short* __restrict__ Vm) {
  __shared__ __align__(16) char smem[32768];
  unsigned short* Alds = (unsigned short*)smem;
  unsigned short* Blds = (unsigned short*)(smem + 16384);
  int bid = blockIdx.x;
  int nt = bid & 7, mt = (bid >> 3) & 3;
  int rest = bid >> 5;
  int p = rest % 3, b = rest / 3;
  int m0 = mt * 128, n0 = nt * 128;
  const unsigned short* A = wb + (size_t)p * NC * NC + (size_t)m0 * NC;
  const unsigned short* Bx = xt + (size_t)b * NPIX * NC + (size_t)n0 * NC;
  int t = threadIdx.x;
  int lane = t & 63, wid = t >> 6;
  int wm = (wid >> 1) * 64, wn = (wid & 1) * 64;
  f32x4 acc[4][4] = {};
  for (int k0 = 0; k0 < NC; k0 += 64) {
#pragma unroll
    for (int i = 0; i < 4; i++) {
      int idx = i * 256 + t;
      int row = idx >> 3, col = (idx & 7) * 8;
      gload_lds16(A + (size_t)row * NC + k0 + col, &Alds[idx * 8]);
    }
#pragma unroll
    for (int i = 0; i < 4; i++) {
      int idx = i * 256 + t;
      int row = idx >> 3, col = (idx & 7) * 8;
      gload_lds16(Bx + (size_t)row * NC + k0 + col, &Blds[idx * 8]);
    }
    __syncthreads();
#pragma unroll
    for (int ks = 0; ks < 2; ks++) {
      int kk = ks * 32 + ((lane >> 4) << 3);
      bf16x8 af[4], bfr[4];
#pragma unroll
      for (int f = 0; f < 4; f++)
        af[f] = *(const bf16x8*)&Alds[(wm + f * 16 + (lane & 15)) * 64 + kk];
#pragma unroll
      for (int f = 0; f < 4; f++)
        bfr[f] = *(const bf16x8*)&Blds[(wn + f * 16 + (lane & 15)) * 64 + kk];
#pragma unroll
      for (int fm = 0; fm < 4; fm++)
#pragma unroll
        for (int fn = 0; fn < 4; fn++)
          acc[fm][fn] = __builtin_amdgcn_mfma_f32_16x16x32_bf16(af[fm], bfr[fn], acc[fm][fn], 0, 0, 0);
    }
    __syncthreads();  // last iter: all LDS reads done -> safe to reuse smem below
  }
  // 512^-0.5 * log2(e): softmax runs in exp2 domain
  const float scale = 0.044194173824159216f * 1.4426950408889634f;
  // ---- build final-layout 32KB tile in LDS ----
  if (p == 2) {
#pragma unroll
    for (int fm = 0; fm < 4; fm++) {
#pragma unroll
      for (int r = 0; r < 4; r++) {
        int d = wm + fm * 16 + ((lane >> 4) << 2) + r;
        float bv = vb[m0 + d];
#pragma unroll
        for (int fn = 0; fn < 4; fn++) {
          int jloc = wn + fn * 16 + (lane & 15);
          int sub = jloc >> 6, jl = jloc & 63;
          int c2 = jl >> 4, h5 = (jl >> 3) & 1, j8 = jl & 7;
          *(unsigned short*)(smem + sub * 16384 +
                             ((((c2 * 2 + h5) * 128 + d) * 8 + j8) * 2)) =
              f2bf(acc[fm][fn][r] + bv);
        }
      }
    }
  } else if (p == 1) {
#pragma unroll
    for (int fm = 0; fm < 4; fm++) {
      int e0 = wm + fm * 16 + ((lane >> 4) << 2);
#pragma unroll
      for (int fn = 0; fn < 4; fn++) {
        int jloc = wn + fn * 16 + (lane & 15);
        int jg = n0 + jloc;
        int sub = jloc >> 6, jl = jloc & 63;
        u16x4 o;
#pragma unroll
        for (int r = 0; r < 4; r++) {
          float v = acc[fm][fn][r] + kb[m0 + e0 + r];
          v += rh[(m0 + e0 + r) * 32 + (jg & 31)] + rw[(m0 + e0 + r) * 32 + (jg >> 5)];
          o[r] = f2bf(v);
        }
        *(u16x4*)(smem + sub * 16384 + jl * 256 + ((2 * e0) ^ ((jl & 7) << 4))) = o;
      }
    }
  } else {
#pragma unroll
    for (int fm = 0; fm < 4; fm++) {
      int e0 = wm + fm * 16 + ((lane >> 4) << 2);
#pragma unroll
      for (int fn = 0; fn < 4; fn++) {
        int ncol = wn + fn * 16 + (lane & 15);
        u16x4 o;
#pragma unroll
        for (int r = 0; r < 4; r++)
          o[r] = f2bf((acc[fm][fn][r] + qb[m0 + e0 + r]) * scale);
        *(u16x4*)(smem + ncol * 256 + 2 * e0) = o;
      }
    }
  }
  __syncthreads();
  // ---- coalesced copy-out: 8 x 16B per thread ----
  char* gdst;
  if (p == 0)
    gdst = (char*)(Qs + ((size_t)((b * NHEADS + mt) * NPIX + n0)) * NEMB);
  else if (p == 1)
    gdst = (char*)(Kn + (size_t)(b * NHEADS + mt) * 131072 + (size_t)(n0 >> 6) * 8192);
  else
    gdst = (char*)(Vm + (size_t)(b * NHEADS + mt) * 131072 + (size_t)(n0 >> 6) * 8192);
#pragma unroll
  for (int i = 0; i < 8; i++)
    *(u16x8*)(gdst + i * 4096 + t * 16) = *(const u16x8*)(smem + i * 4096 + t * 16);
}

// ---------- flash attention v12: K LDS-staged, V direct frag-order with ----------
// ---------- V-loads issued BEFORE K-prefetch (vmcnt FIFO fix for r11)   ----------
// Per tile: (1) 16 V frag loads (1KB coalesced, L2) issued first; (2) K prefetch
// gload_lds; (3) QK^T from K LDS; (4) exp2/pack covers V latency; (5) PV waits
// vmcnt(4) only (K prefetch stays outstanding); (6) barrier drains K prefetch,
// which had the whole tile to land. LDS frag reads halve -> b128 overhead halves.
__global__ __launch_bounds__(256, 2) void k_attn(
    const unsigned short* __restrict__ Qs, const unsigned short* __restrict__ Kp,
    const unsigned short* __restrict__ Vp, float* __restrict__ out) {
  __shared__ __align__(16) char smem[32768];  // K dbuf 2x16KB
  int bid = blockIdx.x;
  int pair = bid & 63;                        // b*4+hd; i-tiles of a pair share bid%8 -> XCD
  int b = pair >> 2, hd = pair & 3;
  int i0 = (bid >> 6) * 128;
  int t = threadIdx.x, w = t >> 6, lane = t & 63;
  int l31 = lane & 31, hi5 = lane >> 5;
  const unsigned short* Qb = Qs + (size_t)pair * NPIX * NEMB;
  const char* Kpb = (const char*)(Kp + (size_t)pair * 131072);
  const unsigned short* Vg = Vp + (size_t)pair * 131072;

  // Q B-frags: lane holds Q[q = i0+w*32+l31][d8*16 + hi5*8 + e]
  bf16x8 qf[8];
  {
    const unsigned short* qr = Qb + (size_t)(i0 + w * 32 + l31) * NEMB + hi5 * 8;
#pragma unroll
    for (int d8 = 0; d8 < 8; d8++) qf[d8] = *(const bf16x8*)(qr + d8 * 16);
  }
  f32x16 yacc[4] = {};
  float l = 0.f;

  // prologue: stage K tile 0 into buf 0
#pragma unroll
  for (int r = 0; r < 4; r++)
    gload_lds16(Kpb + r * 4096 + t * 16, smem + r * 4096 + t * 16);
  __syncthreads();

  for (int tt = 0; tt < 16; tt++) {
    int cur = tt & 1;
    // (1) V fragment loads FIRST (vmcnt FIFO: must precede K prefetch so the
    //     pre-PV wait leaves the K gload_lds outstanding)
    bf16x8 vf[4][4];
#pragma unroll
    for (int c2 = 0; c2 < 4; c2++)
#pragma unroll
      for (int ds = 0; ds < 4; ds++)
        vf[c2][ds] = *(const bf16x8*)(
            Vg + ((((size_t)tt * 4 + c2) * 2 + hi5) * 128 + ds * 32 + l31) * 8);
    // (2) K prefetch for next tile
    if (tt < 15) {
      const char* kn = Kpb + (tt + 1) * 16384;
      char* kd = smem + (cur ^ 1) * 16384;
#pragma unroll
      for (int r = 0; r < 4; r++)
        gload_lds16(kn + r * 4096 + t * 16, kd + r * 4096 + t * 16);
    }
    const char* Kl = smem + cur * 16384;
    // (3) S^T = K Q^T : per lane, 32 S-values for q = l31
    f32x16 sacc[2] = {};
    {
      int swz = (l31 & 7) << 4;
#pragma unroll
      for (int d8 = 0; d8 < 8; d8++) {
        int colb = (d8 * 32 + hi5 * 16) ^ swz;
        bf16x8 k0 = *(const bf16x8*)(Kl + l31 * 256 + colb);
        bf16x8 k1 = *(const bf16x8*)(Kl + (32 + l31) * 256 + colb);
        __builtin_amdgcn_s_setprio(1);
        sacc[0] = __builtin_amdgcn_mfma_f32_32x32x16_bf16(k0, qf[d8], sacc[0], 0, 0, 0);
        sacc[1] = __builtin_amdgcn_mfma_f32_32x32x16_bf16(k1, qf[d8], sacc[1], 0, 0, 0);
        __builtin_amdgcn_s_setprio(0);
      }
    }
    // (4) P = exp2(S) directly (no max; bounded logits — r7 analysis)
    float rs0 = 0.f, rs1 = 0.f, rs2 = 0.f, rs3 = 0.f;
#pragma unroll
    for (int c = 0; c < 2; c++)
#pragma unroll
      for (int i = 0; i < 16; i += 4) {
        float p0 = exp2f(sacc[c][i + 0]);
        float p1 = exp2f(sacc[c][i + 1]);
        float p2 = exp2f(sacc[c][i + 2]);
        float p3 = exp2f(sacc[c][i + 3]);
        sacc[c][i + 0] = p0; sacc[c][i + 1] = p1;
        sacc[c][i + 2] = p2; sacc[c][i + 3] = p3;
        rs0 += p0; rs1 += p1; rs2 += p2; rs3 += p3;
      }
    l += (rs0 + rs1) + (rs2 + rs3);
    // pack P to bf16 pairs, assemble PV B-frags via permlane32_swap (r9 algebra)
    unsigned up[2][4][2];
#pragma unroll
    for (int c = 0; c < 2; c++)
#pragma unroll
      for (int g = 0; g < 4; g++) {
        up[c][g][0] = cvtpk_bf16(sacc[c][4 * g + 0], sacc[c][4 * g + 1]);
        up[c][g][1] = cvtpk_bf16(sacc[c][4 * g + 2], sacc[c][4 * g + 3]);
      }
    bf16x8 pf[4];
#pragma unroll
    for (int c2 = 0; c2 < 4; c2++) {
      int c = c2 >> 1, gA = (c2 & 1) * 2, gB = gA + 1;
      unsigned a0 = up[c][gA][0], b0 = up[c][gB][0];
      unsigned a1 = up[c][gA][1], b1 = up[c][gB][1];
      asm("v_permlane32_swap_b32 %0, %1" : "+v"(a0), "+v"(b0));
      asm("v_permlane32_swap_b32 %0, %1" : "+v"(a1), "+v"(b1));
      unsigned wd[4] = { a0, a1, b0, b1 };
      pf[c2] = *(bf16x8*)wd;
    }
    // (5) y^T += V^T P^T (vf from global, waits vmcnt(4) only)
    __builtin_amdgcn_s_setprio(1);
#pragma unroll
    for (int c2 = 0; c2 < 4; c2++)
#pragma unroll
      for (int ds = 0; ds < 4; ds++)
        yacc[ds] = __builtin_amdgcn_mfma_f32_32x32x16_bf16(vf[c2][ds], pf[c2], yacc[ds], 0, 0, 0);
    __builtin_amdgcn_s_setprio(0);
    // (6) barrier: K[cur] reads done; K prefetch (issued at tile top) drained cheaply
    __syncthreads();
  }
  // epilogue: combine l across halves once; q = i0+w*32+l31 per lane;
  // d = ds*32 + rg*8 + hi5*4 + (0..3)
  float ltot = l + __shfl_xor(l, 32);
  float invl = 1.0f / ltot;
  int q = i0 + w * 32 + l31;
  float* orow = out + ((size_t)(b * NC + hd * NEMB + (q >> 3))) * NPIX + (q & 7) * NEMB;
#pragma unroll
  for (int ds = 0; ds < 4; ds++)
#pragma unroll
    for (int rg = 0; rg < 4; rg++) {
      f32x4 v;
#pragma unroll
      for (int i = 0; i < 4; i++) v[i] = yacc[ds][rg * 4 + i] * invl;
      *(f32x4*)(orow + ds * 32 + rg * 8 + hi5 * 4) = v;
    }
}

extern "C" void kernel_launch(void* const* d_in, const int* in_sizes, int n_in,
                              void* d_out, int out_size, void* d_ws, size_t ws_size,
                              hipStream_t stream) {
  const float* x  = (const float*)d_in[0];
  const float* wq = (const float*)d_in[1];
  const float* qb = (const float*)d_in[2];
  const float* wk = (const float*)d_in[3];
  const float* kb = (const float*)d_in[4];
  const float* wv = (const float*)d_in[5];
  const float* vb = (const float*)d_in[6];
  const float* rh = (const float*)d_in[7];
  const float* rw = (const float*)d_in[8];
  float* out = (float*)d_out;
  char* ws = (char*)d_ws;
  // ws layout (bytes): xt 16,777,216 | wb 1,572,864 | Q 16,777,216 | K 16,777,216 | V 16,777,216
  unsigned short* xt = (unsigned short*)(ws);
  unsigned short* wb = (unsigned short*)(ws + 16777216);
  unsigned short* Q  = (unsigned short*)(ws + 18350080);
  unsigned short* K  = (unsigned short*)(ws + 35127296);
  unsigned short* V  = (unsigned short*)(ws + 51904512);
  k_prep<<<2304, 256, 0, stream>>>(x, xt, wq, wk, wv, wb);
  k_qkv<<<1536, 256, 0, stream>>>(wb, xt, qb, kb, vb, rh, rw, Q, K, V);
  k_attn<<<512, 256, 0, stream>>>(Q, K, V, out);
}

// Round 16
// 101.751 us; speedup vs baseline: 1.0295x; 1.0295x over previous
//
#include <hip/hip_runtime.h>
#include <hip/hip_bf16.h>
#include <cstdint>

#define NB 16
#define NC 512
#define NPIX 1024
#define NHEADS 4
#define NEMB 128

typedef short bf16x8 __attribute__((ext_vector_type(8)));
typedef float f32x4 __attribute__((ext_vector_type(4)));
typedef float f32x16 __attribute__((ext_vector_type(16)));
typedef unsigned short u16x4 __attribute__((ext_vector_type(4)));
typedef unsigned short u16x8 __attribute__((ext_vector_type(8)));

__device__ __forceinline__ unsigned short f2bf(float f) {
  union { float f; unsigned u; } c; c.f = f;
  return (unsigned short)((c.u + 0x7FFFu + ((c.u >> 16) & 1u)) >> 16);
}

__device__ __forceinline__ unsigned cvtpk_bf16(float lo, float hi) {
  unsigned r;
  asm("v_cvt_pk_bf16_f32 %0, %1, %2" : "=v"(r) : "v"(lo), "v"(hi));
  return r;
}

__device__ __forceinline__ void gload_lds16(const void* g, void* l) {
  __builtin_amdgcn_global_load_lds(
      (const __attribute__((address_space(1))) unsigned int*)g,
      (__attribute__((address_space(3))) unsigned int*)l, 16, 0, 0);
}

// ---------- merged prep: blocks 0..2047 transpose x -> xt; 2048..2303 convert w ----------
__global__ void k_prep(const float* __restrict__ x, unsigned short* __restrict__ xt,
                       const float* __restrict__ wq, const float* __restrict__ wk,
                       const float* __restrict__ wv, unsigned short* __restrict__ wb) {
  int bid = blockIdx.x;
  if (bid >= 2048) {
    int wbid = bid - 2048;
    for (int i = wbid * 256 + threadIdx.x; i < 3 * 65536; i += 256 * 256) {
      int p = i >> 16, idx = i & 65535;
      const float* src = p == 0 ? wq : (p == 1 ? wk : wv);
      float4 v = ((const float4*)src)[idx];
      u16x4 o = { f2bf(v.x), f2bf(v.y), f2bf(v.z), f2bf(v.w) };
      ((u16x4*)(wb + (size_t)p * NC * NC))[idx] = o;
    }
    return;
  }
  __shared__ float tile[4][32][33];
  int nt = bid & 31, ct4 = (bid >> 5) & 3, b = bid >> 7;
  int n0 = nt * 32, c0 = ct4 * 128;
  int t = threadIdx.x;
  int r = t >> 3, q = t & 7;
#pragma unroll
  for (int s = 0; s < 4; s++) {
    float4 v = *(const float4*)(x + ((size_t)(b * NC + c0 + s * 32 + r)) * NPIX + n0 + q * 4);
    tile[s][r][q * 4 + 0] = v.x; tile[s][r][q * 4 + 1] = v.y;
    tile[s][r][q * 4 + 2] = v.z; tile[s][r][q * 4 + 3] = v.w;
  }
  __syncthreads();
#pragma unroll
  for (int pass = 0; pass < 2; pass++) {
    int idx = pass * 256 + t;
    int n = idx >> 4;
    int c8 = (idx & 15) * 8;
    int s = c8 >> 5, cl = c8 & 31;
    u16x8 o;
#pragma unroll
    for (int j = 0; j < 8; j++) o[j] = f2bf(tile[s][cl + j][n]);
    *(u16x8*)(xt + ((size_t)(b * NPIX + n0 + n)) * NC + c0 + c8) = o;
  }
}

// ---------- QKV projection GEMM (r14: LDS-restaged coalesced epilogue) ----------
// p==0: Q -> (acc+bias)*scale*log2e, [b][hd][n][e]  (exp2-domain)
// p==1: K -> acc+bias+rh+rw, tiles 16KB: elem(jl,e) at byte jl*256 + ((2e)^((jl&7)<<4))
// p==2: V -> acc+bias,       tiles 16KB: elem(d,jl) at byte d*128 + ((2jl)^((d&7)<<4))
__global__ __launch_bounds__(256, 3) void k_qkv(
    const unsigned short* __restrict__ wb, const unsigned short* __restrict__ xt,
    const float* __restrict__ qb, const float* __restrict__ kb, const float* __restrict__ vb,
    const float* __restrict__ rh, const float* __restrict__ rw,
    unsigned short* __restrict__ Qs, unsigned short* __restrict__ Kn,
    unsigned short* __restrict__ Vm) {
  __shared__ __align__(16) char smem[32768];
  unsigned short* Alds = (unsigned short*)smem;
  unsigned short* Blds = (unsigned short*)(smem + 16384);
  int bid = blockIdx.x;
  int nt = bid & 7, mt = (bid >> 3) & 3;
  int rest = bid >> 5;
  int p = rest % 3, b = rest / 3;
  int m0 = mt * 128, n0 = nt * 128;
  const unsigned short* A = wb + (size_t)p * NC * NC + (size_t)m0 * NC;
  const unsigned short* Bx = xt + (size_t)b * NPIX * NC + (size_t)n0 * NC;
  int t = threadIdx.x;
  int lane = t & 63, wid = t >> 6;
  int wm = (wid >> 1) * 64, wn = (wid & 1) * 64;
  f32x4 acc[4][4] = {};
  for (int k0 = 0; k0 < NC; k0 += 64) {
#pragma unroll
    for (int i = 0; i < 4; i++) {
      int idx = i * 256 + t;
      int row = idx >> 3, col = (idx & 7) * 8;
      gload_lds16(A + (size_t)row * NC + k0 + col, &Alds[idx * 8]);
    }
#pragma unroll
    for (int i = 0; i < 4; i++) {
      int idx = i * 256 + t;
      int row = idx >> 3, col = (idx & 7) * 8;
      gload_lds16(Bx + (size_t)row * NC + k0 + col, &Blds[idx * 8]);
    }
    __syncthreads();
#pragma unroll
    for (int ks = 0; ks < 2; ks++) {
      int kk = ks * 32 + ((lane >> 4) << 3);
      bf16x8 af[4], bfr[4];
#pragma unroll
      for (int f = 0; f < 4; f++)
        af[f] = *(const bf16x8*)&Alds[(wm + f * 16 + (lane & 15)) * 64 + kk];
#pragma unroll
      for (int f = 0; f < 4; f++)
        bfr[f] = *(const bf16x8*)&Blds[(wn + f * 16 + (lane & 15)) * 64 + kk];
#pragma unroll
      for (int fm = 0; fm < 4; fm++)
#pragma unroll
        for (int fn = 0; fn < 4; fn++)
          acc[fm][fn] = __builtin_amdgcn_mfma_f32_16x16x32_bf16(af[fm], bfr[fn], acc[fm][fn], 0, 0, 0);
    }
    __syncthreads();  // last iter: all LDS reads done -> safe to reuse smem below
  }
  // 512^-0.5 * log2(e): softmax runs in exp2 domain
  const float scale = 0.044194173824159216f * 1.4426950408889634f;
  // ---- build final-layout 32KB tile in LDS ----
  if (p == 2) {
#pragma unroll
    for (int fm = 0; fm < 4; fm++) {
#pragma unroll
      for (int r = 0; r < 4; r++) {
        int d = wm + fm * 16 + ((lane >> 4) << 2) + r;
        float bv = vb[m0 + d];
#pragma unroll
        for (int fn = 0; fn < 4; fn++) {
          int jloc = wn + fn * 16 + (lane & 15);
          int sub = jloc >> 6, jl = jloc & 63;
          *(unsigned short*)(smem + sub * 16384 + d * 128 + ((2 * jl) ^ ((d & 7) << 4))) =
              f2bf(acc[fm][fn][r] + bv);
        }
      }
    }
  } else if (p == 1) {
#pragma unroll
    for (int fm = 0; fm < 4; fm++) {
      int e0 = wm + fm * 16 + ((lane >> 4) << 2);
#pragma unroll
      for (int fn = 0; fn < 4; fn++) {
        int jloc = wn + fn * 16 + (lane & 15);
        int jg = n0 + jloc;
        int sub = jloc >> 6, jl = jloc & 63;
        u16x4 o;
#pragma unroll
        for (int r = 0; r < 4; r++) {
          float v = acc[fm][fn][r] + kb[m0 + e0 + r];
          v += rh[(m0 + e0 + r) * 32 + (jg & 31)] + rw[(m0 + e0 + r) * 32 + (jg >> 5)];
          o[r] = f2bf(v);
        }
        *(u16x4*)(smem + sub * 16384 + jl * 256 + ((2 * e0) ^ ((jl & 7) << 4))) = o;
      }
    }
  } else {
#pragma unroll
    for (int fm = 0; fm < 4; fm++) {
      int e0 = wm + fm * 16 + ((lane >> 4) << 2);
#pragma unroll
      for (int fn = 0; fn < 4; fn++) {
        int ncol = wn + fn * 16 + (lane & 15);
        u16x4 o;
#pragma unroll
        for (int r = 0; r < 4; r++)
          o[r] = f2bf((acc[fm][fn][r] + qb[m0 + e0 + r]) * scale);
        *(u16x4*)(smem + ncol * 256 + 2 * e0) = o;
      }
    }
  }
  __syncthreads();
  // ---- coalesced copy-out: 8 x 16B per thread ----
  char* gdst;
  if (p == 0)
    gdst = (char*)(Qs + ((size_t)((b * NHEADS + mt) * NPIX + n0)) * NEMB);
  else if (p == 1)
    gdst = (char*)(Kn + (size_t)(b * NHEADS + mt) * 131072 + (size_t)(n0 >> 6) * 8192);
  else
    gdst = (char*)(Vm + (size_t)(b * NHEADS + mt) * 131072 + (size_t)(n0 >> 6) * 8192);
#pragma unroll
  for (int i = 0; i < 8; i++)
    *(u16x8*)(gdst + i * 4096 + t * 16) = *(const u16x8*)(smem + i * 4096 + t * 16);
}

// ---------- flash attention (r14 structure + early V ds_reads) ----------
// Swapped QK^T (32x32 MFMA), in-register exp2 softmax (no max — bounded logits),
// permlane pack, K/V pre-swizzled -> linear gload_lds staging, dbuf, 1 barrier/tile.
// NEW: all 16 V frag ds_reads issue right after QK^T — V[cur] LDS is stable all
// tile (prefetch writes buf^1 only), so exp2/pack VALU covers their latency and
// the PV phase is pure back-to-back MFMA. +64 VGPR, occupancy unchanged (LDS-capped).
__global__ __launch_bounds__(256, 2) void k_attn(
    const unsigned short* __restrict__ Qs, const unsigned short* __restrict__ Kp,
    const unsigned short* __restrict__ Vp, float* __restrict__ out) {
  __shared__ __align__(16) char smem[65536];  // K dbuf 2x16KB @0, V dbuf 2x16KB @32768
  int bid = blockIdx.x;
  int pair = bid & 63;                        // b*4+hd; i-tiles of a pair share bid%8 -> XCD
  int b = pair >> 2, hd = pair & 3;
  int i0 = (bid >> 6) * 128;
  int t = threadIdx.x, w = t >> 6, lane = t & 63;
  int l31 = lane & 31, hi5 = lane >> 5;
  const unsigned short* Qb = Qs + (size_t)pair * NPIX * NEMB;
  const char* Kpb = (const char*)(Kp + (size_t)pair * 131072);
  const char* Vpb = (const char*)(Vp + (size_t)pair * 131072);

  // Q B-frags: lane holds Q[q = i0+w*32+l31][d8*16 + hi5*8 + e]
  bf16x8 qf[8];
  {
    const unsigned short* qr = Qb + (size_t)(i0 + w * 32 + l31) * NEMB + hi5 * 8;
#pragma unroll
    for (int d8 = 0; d8 < 8; d8++) qf[d8] = *(const bf16x8*)(qr + d8 * 16);
  }
  f32x16 yacc[4] = {};
  float l = 0.f;

  // prologue: stage tile 0 into buf 0
#pragma unroll
  for (int r = 0; r < 4; r++) {
    gload_lds16(Kpb + r * 4096 + t * 16, smem + r * 4096 + t * 16);
    gload_lds16(Vpb + r * 4096 + t * 16, smem + 32768 + r * 4096 + t * 16);
  }
  __syncthreads();

  for (int tt = 0; tt < 16; tt++) {
    int cur = tt & 1;
    if (tt < 15) {  // prefetch next tile into other buffer (drained by barrier at loop end)
      const char* kn = Kpb + (tt + 1) * 16384;
      const char* vn = Vpb + (tt + 1) * 16384;
      char* kd = smem + (cur ^ 1) * 16384;
      char* vd = smem + 32768 + (cur ^ 1) * 16384;
#pragma unroll
      for (int r = 0; r < 4; r++) {
        gload_lds16(kn + r * 4096 + t * 16, kd + r * 4096 + t * 16);
        gload_lds16(vn + r * 4096 + t * 16, vd + r * 4096 + t * 16);
      }
    }
    const char* Kl = smem + cur * 16384;
    const char* Vl = smem + 32768 + cur * 16384;
    int swz = (l31 & 7) << 4;
    // S^T = K Q^T : per lane, 32 S-values for q = l31 (k rows per C-layout)
    f32x16 sacc[2] = {};
#pragma unroll
    for (int d8 = 0; d8 < 8; d8++) {
      int colb = (d8 * 32 + hi5 * 16) ^ swz;
      bf16x8 k0 = *(const bf16x8*)(Kl + l31 * 256 + colb);
      bf16x8 k1 = *(const bf16x8*)(Kl + (32 + l31) * 256 + colb);
      __builtin_amdgcn_s_setprio(1);
      sacc[0] = __builtin_amdgcn_mfma_f32_32x32x16_bf16(k0, qf[d8], sacc[0], 0, 0, 0);
      sacc[1] = __builtin_amdgcn_mfma_f32_32x32x16_bf16(k1, qf[d8], sacc[1], 0, 0, 0);
      __builtin_amdgcn_s_setprio(0);
    }
    // EARLY V fragment ds_reads: latency hides under the exp2/pack VALU phase
    bf16x8 vfr[4][4];
#pragma unroll
    for (int c2 = 0; c2 < 4; c2++) {
      int colb = (c2 * 32 + hi5 * 16) ^ swz;
#pragma unroll
      for (int ds = 0; ds < 4; ds++)
        vfr[c2][ds] = *(const bf16x8*)(Vl + (ds * 32 + l31) * 128 + colb);
    }
    // P = exp2(S) directly (no max; bounded logits — r7 analysis); 4 independent
    // sum accumulators; l keeps own-half partial sums (combined in epilogue).
    float rs0 = 0.f, rs1 = 0.f, rs2 = 0.f, rs3 = 0.f;
#pragma unroll
    for (int c = 0; c < 2; c++)
#pragma unroll
      for (int i = 0; i < 16; i += 4) {
        float p0 = exp2f(sacc[c][i + 0]);
        float p1 = exp2f(sacc[c][i + 1]);
        float p2 = exp2f(sacc[c][i + 2]);
        float p3 = exp2f(sacc[c][i + 3]);
        sacc[c][i + 0] = p0; sacc[c][i + 1] = p1;
        sacc[c][i + 2] = p2; sacc[c][i + 3] = p3;
        rs0 += p0; rs1 += p1; rs2 += p2; rs3 += p3;
      }
    l += (rs0 + rs1) + (rs2 + rs3);
    // pack P to bf16 pairs, assemble PV B-frags via permlane32_swap (r9 algebra)
    unsigned up[2][4][2];
#pragma unroll
    for (int c = 0; c < 2; c++)
#pragma unroll
      for (int g = 0; g < 4; g++) {
        up[c][g][0] = cvtpk_bf16(sacc[c][4 * g + 0], sacc[c][4 * g + 1]);
        up[c][g][1] = cvtpk_bf16(sacc[c][4 * g + 2], sacc[c][4 * g + 3]);
      }
    bf16x8 pf[4];
#pragma unroll
    for (int c2 = 0; c2 < 4; c2++) {
      int c = c2 >> 1, gA = (c2 & 1) * 2, gB = gA + 1;
      unsigned a0 = up[c][gA][0], b0 = up[c][gB][0];
      unsigned a1 = up[c][gA][1], b1 = up[c][gB][1];
      asm("v_permlane32_swap_b32 %0, %1" : "+v"(a0), "+v"(b0));
      asm("v_permlane32_swap_b32 %0, %1" : "+v"(a1), "+v"(b1));
      unsigned wd[4] = { a0, a1, b0, b1 };
      pf[c2] = *(bf16x8*)wd;
    }
    // y^T += V^T P^T : pure back-to-back MFMA (vfr already in registers)
    __builtin_amdgcn_s_setprio(1);
#pragma unroll
    for (int c2 = 0; c2 < 4; c2++)
#pragma unroll
      for (int ds = 0; ds < 4; ds++)
        yacc[ds] = __builtin_amdgcn_mfma_f32_32x32x16_bf16(vfr[c2][ds], pf[c2], yacc[ds], 0, 0, 0);
    __builtin_amdgcn_s_setprio(0);
    if (tt < 15) __syncthreads();  // all reads of cur done; buf cur^1 becomes ready
  }
  // epilogue: combine l across halves once; q = i0+w*32+l31 per lane;
  // d = ds*32 + rg*8 + hi5*4 + (0..3)
  float ltot = l + __shfl_xor(l, 32);
  float invl = 1.0f / ltot;
  int q = i0 + w * 32 + l31;
  float* orow = out + ((size_t)(b * NC + hd * NEMB + (q >> 3))) * NPIX + (q & 7) * NEMB;
#pragma unroll
  for (int ds = 0; ds < 4; ds++)
#pragma unroll
    for (int rg = 0; rg < 4; rg++) {
      f32x4 v;
#pragma unroll
      for (int i = 0; i < 4; i++) v[i] = yacc[ds][rg * 4 + i] * invl;
      *(f32x4*)(orow + ds * 32 + rg * 8 + hi5 * 4) = v;
    }
}

extern "C" void kernel_launch(void* const* d_in, const int* in_sizes, int n_in,
                              void* d_out, int out_size, void* d_ws, size_t ws_size,
                              hipStream_t stream) {
  const float* x  = (const float*)d_in[0];
  const float* wq = (const float*)d_in[1];
  const float* qb = (const float*)d_in[2];
  const float* wk = (const float*)d_in[3];
  const float* kb = (const float*)d_in[4];
  const float* wv = (const float*)d_in[5];
  const float* vb = (const float*)d_in[6];
  const float* rh = (const float*)d_in[7];
  const float* rw = (const float*)d_in[8];
  float* out = (float*)d_out;
  char* ws = (char*)d_ws;
  // ws layout (bytes): xt 16,777,216 | wb 1,572,864 | Q 16,777,216 | K 16,777,216 | V 16,777,216
  unsigned short* xt = (unsigned short*)(ws);
  unsigned short* wb = (unsigned short*)(ws + 16777216);
  unsigned short* Q  = (unsigned short*)(ws + 18350080);
  unsigned short* K  = (unsigned short*)(ws + 35127296);
  unsigned short* V  = (unsigned short*)(ws + 51904512);
  k_prep<<<2304, 256, 0, stream>>>(x, xt, wq, wk, wv, wb);
  k_qkv<<<1536, 256, 0, stream>>>(wb, xt, qb, kb, vb, rh, rw, Q, K, V);
  k_attn<<<512, 256, 0, stream>>>(Q, K, V, out);
}

// Round 17
// 101.327 us; speedup vs baseline: 1.0338x; 1.0042x over previous
//
#include <hip/hip_runtime.h>
#include <hip/hip_bf16.h>
#include <cstdint>

#define NB 16
#define NC 512
#define NPIX 1024
#define NHEADS 4
#define NEMB 128

typedef short bf16x8 __attribute__((ext_vector_type(8)));
typedef float f32x4 __attribute__((ext_vector_type(4)));
typedef float f32x16 __attribute__((ext_vector_type(16)));
typedef unsigned short u16x4 __attribute__((ext_vector_type(4)));
typedef unsigned short u16x8 __attribute__((ext_vector_type(8)));

__device__ __forceinline__ unsigned short f2bf(float f) {
  union { float f; unsigned u; } c; c.f = f;
  return (unsigned short)((c.u + 0x7FFFu + ((c.u >> 16) & 1u)) >> 16);
}

__device__ __forceinline__ unsigned cvtpk_bf16(float lo, float hi) {
  unsigned r;
  asm("v_cvt_pk_bf16_f32 %0, %1, %2" : "=v"(r) : "v"(lo), "v"(hi));
  return r;
}

__device__ __forceinline__ void gload_lds16(const void* g, void* l) {
  __builtin_amdgcn_global_load_lds(
      (const __attribute__((address_space(1))) unsigned int*)g,
      (__attribute__((address_space(3))) unsigned int*)l, 16, 0, 0);
}

// ---------- merged prep: blocks 0..2047 transpose x -> xt; 2048..2303 convert w ----------
__global__ void k_prep(const float* __restrict__ x, unsigned short* __restrict__ xt,
                       const float* __restrict__ wq, const float* __restrict__ wk,
                       const float* __restrict__ wv, unsigned short* __restrict__ wb) {
  int bid = blockIdx.x;
  if (bid >= 2048) {
    int wbid = bid - 2048;
    for (int i = wbid * 256 + threadIdx.x; i < 3 * 65536; i += 256 * 256) {
      int p = i >> 16, idx = i & 65535;
      const float* src = p == 0 ? wq : (p == 1 ? wk : wv);
      float4 v = ((const float4*)src)[idx];
      u16x4 o = { f2bf(v.x), f2bf(v.y), f2bf(v.z), f2bf(v.w) };
      ((u16x4*)(wb + (size_t)p * NC * NC))[idx] = o;
    }
    return;
  }
  __shared__ float tile[4][32][33];
  int nt = bid & 31, ct4 = (bid >> 5) & 3, b = bid >> 7;
  int n0 = nt * 32, c0 = ct4 * 128;
  int t = threadIdx.x;
  int r = t >> 3, q = t & 7;
#pragma unroll
  for (int s = 0; s < 4; s++) {
    float4 v = *(const float4*)(x + ((size_t)(b * NC + c0 + s * 32 + r)) * NPIX + n0 + q * 4);
    tile[s][r][q * 4 + 0] = v.x; tile[s][r][q * 4 + 1] = v.y;
    tile[s][r][q * 4 + 2] = v.z; tile[s][r][q * 4 + 3] = v.w;
  }
  __syncthreads();
#pragma unroll
  for (int pass = 0; pass < 2; pass++) {
    int idx = pass * 256 + t;
    int n = idx >> 4;
    int c8 = (idx & 15) * 8;
    int s = c8 >> 5, cl = c8 & 31;
    u16x8 o;
#pragma unroll
    for (int j = 0; j < 8; j++) o[j] = f2bf(tile[s][cl + j][n]);
    *(u16x8*)(xt + ((size_t)(b * NPIX + n0 + n)) * NC + c0 + c8) = o;
  }
}

// ---------- QKV projection GEMM (r14: LDS-restaged coalesced epilogue) ----------
// p==0: Q -> (acc+bias)*scale*log2e, [b][hd][n][e]  (exp2-domain)
// p==1: K -> acc+bias+rh+rw, tiles 16KB: elem(jl,e) at byte jl*256 + ((2e)^((jl&7)<<4))
// p==2: V -> acc+bias,       tiles 16KB: elem(d,jl) at byte d*128 + ((2jl)^((d&7)<<4))
__global__ __launch_bounds__(256, 3) void k_qkv(
    const unsigned short* __restrict__ wb, const unsigned short* __restrict__ xt,
    const float* __restrict__ qb, const float* __restrict__ kb, const float* __restrict__ vb,
    const float* __restrict__ rh, const float* __restrict__ rw,
    unsigned short* __restrict__ Qs, unsigned short* __restrict__ Kn,
    unsigned short* __restrict__ Vm) {
  __shared__ __align__(16) char smem[32768];
  unsigned short* Alds = (unsigned short*)smem;
  unsigned short* Blds = (unsigned short*)(smem + 16384);
  int bid = blockIdx.x;
  int nt = bid & 7, mt = (bid >> 3) & 3;
  int rest = bid >> 5;
  int p = rest % 3, b = rest / 3;
  int m0 = mt * 128, n0 = nt * 128;
  const unsigned short* A = wb + (size_t)p * NC * NC + (size_t)m0 * NC;
  const unsigned short* Bx = xt + (size_t)b * NPIX * NC + (size_t)n0 * NC;
  int t = threadIdx.x;
  int lane = t & 63, wid = t >> 6;
  int wm = (wid >> 1) * 64, wn = (wid & 1) * 64;
  f32x4 acc[4][4] = {};
  for (int k0 = 0; k0 < NC; k0 += 64) {
#pragma unroll
    for (int i = 0; i < 4; i++) {
      int idx = i * 256 + t;
      int row = idx >> 3, col = (idx & 7) * 8;
      gload_lds16(A + (size_t)row * NC + k0 + col, &Alds[idx * 8]);
    }
#pragma unroll
    for (int i = 0; i < 4; i++) {
      int idx = i * 256 + t;
      int row = idx >> 3, col = (idx & 7) * 8;
      gload_lds16(Bx + (size_t)row * NC + k0 + col, &Blds[idx * 8]);
    }
    __syncthreads();
#pragma unroll
    for (int ks = 0; ks < 2; ks++) {
      int kk = ks * 32 + ((lane >> 4) << 3);
      bf16x8 af[4], bfr[4];
#pragma unroll
      for (int f = 0; f < 4; f++)
        af[f] = *(const bf16x8*)&Alds[(wm + f * 16 + (lane & 15)) * 64 + kk];
#pragma unroll
      for (int f = 0; f < 4; f++)
        bfr[f] = *(const bf16x8*)&Blds[(wn + f * 16 + (lane & 15)) * 64 + kk];
#pragma unroll
      for (int fm = 0; fm < 4; fm++)
#pragma unroll
        for (int fn = 0; fn < 4; fn++)
          acc[fm][fn] = __builtin_amdgcn_mfma_f32_16x16x32_bf16(af[fm], bfr[fn], acc[fm][fn], 0, 0, 0);
    }
    __syncthreads();  // last iter: all LDS reads done -> safe to reuse smem below
  }
  // 512^-0.5 * log2(e): softmax runs in exp2 domain
  const float scale = 0.044194173824159216f * 1.4426950408889634f;
  // ---- build final-layout 32KB tile in LDS ----
  if (p == 2) {
#pragma unroll
    for (int fm = 0; fm < 4; fm++) {
#pragma unroll
      for (int r = 0; r < 4; r++) {
        int d = wm + fm * 16 + ((lane >> 4) << 2) + r;
        float bv = vb[m0 + d];
#pragma unroll
        for (int fn = 0; fn < 4; fn++) {
          int jloc = wn + fn * 16 + (lane & 15);
          int sub = jloc >> 6, jl = jloc & 63;
          *(unsigned short*)(smem + sub * 16384 + d * 128 + ((2 * jl) ^ ((d & 7) << 4))) =
              f2bf(acc[fm][fn][r] + bv);
        }
      }
    }
  } else if (p == 1) {
#pragma unroll
    for (int fm = 0; fm < 4; fm++) {
      int e0 = wm + fm * 16 + ((lane >> 4) << 2);
#pragma unroll
      for (int fn = 0; fn < 4; fn++) {
        int jloc = wn + fn * 16 + (lane & 15);
        int jg = n0 + jloc;
        int sub = jloc >> 6, jl = jloc & 63;
        u16x4 o;
#pragma unroll
        for (int r = 0; r < 4; r++) {
          float v = acc[fm][fn][r] + kb[m0 + e0 + r];
          v += rh[(m0 + e0 + r) * 32 + (jg & 31)] + rw[(m0 + e0 + r) * 32 + (jg >> 5)];
          o[r] = f2bf(v);
        }
        *(u16x4*)(smem + sub * 16384 + jl * 256 + ((2 * e0) ^ ((jl & 7) << 4))) = o;
      }
    }
  } else {
#pragma unroll
    for (int fm = 0; fm < 4; fm++) {
      int e0 = wm + fm * 16 + ((lane >> 4) << 2);
#pragma unroll
      for (int fn = 0; fn < 4; fn++) {
        int ncol = wn + fn * 16 + (lane & 15);
        u16x4 o;
#pragma unroll
        for (int r = 0; r < 4; r++)
          o[r] = f2bf((acc[fm][fn][r] + qb[m0 + e0 + r]) * scale);
        *(u16x4*)(smem + ncol * 256 + 2 * e0) = o;
      }
    }
  }
  __syncthreads();
  // ---- coalesced copy-out: 8 x 16B per thread ----
  char* gdst;
  if (p == 0)
    gdst = (char*)(Qs + ((size_t)((b * NHEADS + mt) * NPIX + n0)) * NEMB);
  else if (p == 1)
    gdst = (char*)(Kn + (size_t)(b * NHEADS + mt) * 131072 + (size_t)(n0 >> 6) * 8192);
  else
    gdst = (char*)(Vm + (size_t)(b * NHEADS + mt) * 131072 + (size_t)(n0 >> 6) * 8192);
#pragma unroll
  for (int i = 0; i < 8; i++)
    *(u16x8*)(gdst + i * 4096 + t * 16) = *(const u16x8*)(smem + i * 4096 + t * 16);
}

// ---------- flash attention v14: r16 data-path, chunk-pipelined phase order, ----------
// ---------- no setprio fences                                                ----------
// Per tile: chain0 QK^T (sacc0, 8 MFMA) -> chain1 QK^T (sacc1, independent) with
// early V ds_reads between; exp2/pack chunk0 overlaps chain1; PV(c2=0,1) overlaps
// exp2/pack chunk1; PV(c2=2,3) closes. Pure reordering of the r16 math — gives the
// scheduler an MFMA cluster under every VALU burst. setprio brackets removed (they
// fence code motion; never A/B'd in this structure — m190 shows they can hurt).
__global__ __launch_bounds__(256, 2) void k_attn(
    const unsigned short* __restrict__ Qs, const unsigned short* __restrict__ Kp,
    const unsigned short* __restrict__ Vp, float* __restrict__ out) {
  __shared__ __align__(16) char smem[65536];  // K dbuf 2x16KB @0, V dbuf 2x16KB @32768
  int bid = blockIdx.x;
  int pair = bid & 63;                        // b*4+hd; i-tiles of a pair share bid%8 -> XCD
  int b = pair >> 2, hd = pair & 3;
  int i0 = (bid >> 6) * 128;
  int t = threadIdx.x, w = t >> 6, lane = t & 63;
  int l31 = lane & 31, hi5 = lane >> 5;
  const unsigned short* Qb = Qs + (size_t)pair * NPIX * NEMB;
  const char* Kpb = (const char*)(Kp + (size_t)pair * 131072);
  const char* Vpb = (const char*)(Vp + (size_t)pair * 131072);

  // Q B-frags: lane holds Q[q = i0+w*32+l31][d8*16 + hi5*8 + e]
  bf16x8 qf[8];
  {
    const unsigned short* qr = Qb + (size_t)(i0 + w * 32 + l31) * NEMB + hi5 * 8;
#pragma unroll
    for (int d8 = 0; d8 < 8; d8++) qf[d8] = *(const bf16x8*)(qr + d8 * 16);
  }
  f32x16 yacc[4] = {};
  float l = 0.f;

  // prologue: stage tile 0 into buf 0
#pragma unroll
  for (int r = 0; r < 4; r++) {
    gload_lds16(Kpb + r * 4096 + t * 16, smem + r * 4096 + t * 16);
    gload_lds16(Vpb + r * 4096 + t * 16, smem + 32768 + r * 4096 + t * 16);
  }
  __syncthreads();

  for (int tt = 0; tt < 16; tt++) {
    int cur = tt & 1;
    if (tt < 15) {  // prefetch next tile into other buffer (drained by barrier at loop end)
      const char* kn = Kpb + (tt + 1) * 16384;
      const char* vn = Vpb + (tt + 1) * 16384;
      char* kd = smem + (cur ^ 1) * 16384;
      char* vd = smem + 32768 + (cur ^ 1) * 16384;
#pragma unroll
      for (int r = 0; r < 4; r++) {
        gload_lds16(kn + r * 4096 + t * 16, kd + r * 4096 + t * 16);
        gload_lds16(vn + r * 4096 + t * 16, vd + r * 4096 + t * 16);
      }
    }
    const char* Kl = smem + cur * 16384;
    const char* Vl = smem + 32768 + cur * 16384;
    int swz = (l31 & 7) << 4;
    // --- QK^T chain 0: sacc0 (k rows 0..31), 8 serially-dependent MFMAs ---
    f32x16 s0 = (f32x16)(0.0f), s1 = (f32x16)(0.0f);
#pragma unroll
    for (int d8 = 0; d8 < 8; d8++) {
      int colb = (d8 * 32 + hi5 * 16) ^ swz;
      bf16x8 k0 = *(const bf16x8*)(Kl + l31 * 256 + colb);
      s0 = __builtin_amdgcn_mfma_f32_32x32x16_bf16(k0, qf[d8], s0, 0, 0, 0);
    }
    // early V frag ds_reads (needed first at PV c2=0; latency hides under chain1)
    bf16x8 vfr[4][4];
#pragma unroll
    for (int c2 = 0; c2 < 4; c2++) {
      int colb = (c2 * 32 + hi5 * 16) ^ swz;
#pragma unroll
      for (int ds = 0; ds < 4; ds++)
        vfr[c2][ds] = *(const bf16x8*)(Vl + (ds * 32 + l31) * 128 + colb);
    }
    // --- QK^T chain 1: sacc1 (k rows 32..63), independent of chunk-0 VALU below ---
#pragma unroll
    for (int d8 = 0; d8 < 8; d8++) {
      int colb = (d8 * 32 + hi5 * 16) ^ swz;
      bf16x8 k1 = *(const bf16x8*)(Kl + (32 + l31) * 256 + colb);
      s1 = __builtin_amdgcn_mfma_f32_32x32x16_bf16(k1, qf[d8], s1, 0, 0, 0);
    }
    // --- chunk 0: exp2 + sum + pack (overlaps chain-1 MFMAs) ---
    float rs0 = 0.f, rs1 = 0.f, rs2 = 0.f, rs3 = 0.f;
#pragma unroll
    for (int i = 0; i < 16; i += 4) {
      float p0 = exp2f(s0[i + 0]);
      float p1 = exp2f(s0[i + 1]);
      float p2 = exp2f(s0[i + 2]);
      float p3 = exp2f(s0[i + 3]);
      s0[i + 0] = p0; s0[i + 1] = p1; s0[i + 2] = p2; s0[i + 3] = p3;
      rs0 += p0; rs1 += p1; rs2 += p2; rs3 += p3;
    }
    unsigned u0[4][2];
#pragma unroll
    for (int g = 0; g < 4; g++) {
      u0[g][0] = cvtpk_bf16(s0[4 * g + 0], s0[4 * g + 1]);
      u0[g][1] = cvtpk_bf16(s0[4 * g + 2], s0[4 * g + 3]);
    }
    bf16x8 pf01[2];
#pragma unroll
    for (int c2 = 0; c2 < 2; c2++) {
      int gA = c2 * 2, gB = gA + 1;
      unsigned a0 = u0[gA][0], b0 = u0[gB][0];
      unsigned a1 = u0[gA][1], b1 = u0[gB][1];
      asm("v_permlane32_swap_b32 %0, %1" : "+v"(a0), "+v"(b0));
      asm("v_permlane32_swap_b32 %0, %1" : "+v"(a1), "+v"(b1));
      unsigned wd[4] = { a0, a1, b0, b1 };
      pf01[c2] = *(bf16x8*)wd;
    }
    // --- PV c2=0,1 (8 MFMAs; overlaps chunk-1 exp2/pack below) ---
#pragma unroll
    for (int c2 = 0; c2 < 2; c2++)
#pragma unroll
      for (int ds = 0; ds < 4; ds++)
        yacc[ds] = __builtin_amdgcn_mfma_f32_32x32x16_bf16(vfr[c2][ds], pf01[c2], yacc[ds], 0, 0, 0);
    // --- chunk 1: exp2 + sum + pack ---
#pragma unroll
    for (int i = 0; i < 16; i += 4) {
      float p0 = exp2f(s1[i + 0]);
      float p1 = exp2f(s1[i + 1]);
      float p2 = exp2f(s1[i + 2]);
      float p3 = exp2f(s1[i + 3]);
      s1[i + 0] = p0; s1[i + 1] = p1; s1[i + 2] = p2; s1[i + 3] = p3;
      rs0 += p0; rs1 += p1; rs2 += p2; rs3 += p3;
    }
    l += (rs0 + rs1) + (rs2 + rs3);
    unsigned u1[4][2];
#pragma unroll
    for (int g = 0; g < 4; g++) {
      u1[g][0] = cvtpk_bf16(s1[4 * g + 0], s1[4 * g + 1]);
      u1[g][1] = cvtpk_bf16(s1[4 * g + 2], s1[4 * g + 3]);
    }
    bf16x8 pf23[2];
#pragma unroll
    for (int c2 = 0; c2 < 2; c2++) {
      int gA = c2 * 2, gB = gA + 1;
      unsigned a0 = u1[gA][0], b0 = u1[gB][0];
      unsigned a1 = u1[gA][1], b1 = u1[gB][1];
      asm("v_permlane32_swap_b32 %0, %1" : "+v"(a0), "+v"(b0));
      asm("v_permlane32_swap_b32 %0, %1" : "+v"(a1), "+v"(b1));
      unsigned wd[4] = { a0, a1, b0, b1 };
      pf23[c2] = *(bf16x8*)wd;
    }
    // --- PV c2=2,3 ---
#pragma unroll
    for (int c2 = 0; c2 < 2; c2++)
#pragma unroll
      for (int ds = 0; ds < 4; ds++)
        yacc[ds] = __builtin_amdgcn_mfma_f32_32x32x16_bf16(vfr[c2 + 2][ds], pf23[c2], yacc[ds], 0, 0, 0);
    if (tt < 15) __syncthreads();  // all reads of cur done; buf cur^1 becomes ready
  }
  // epilogue: combine l across halves once; q = i0+w*32+l31 per lane;
  // d = ds*32 + rg*8 + hi5*4 + (0..3)
  float ltot = l + __shfl_xor(l, 32);
  float invl = 1.0f / ltot;
  int q = i0 + w * 32 + l31;
  float* orow = out + ((size_t)(b * NC + hd * NEMB + (q >> 3))) * NPIX + (q & 7) * NEMB;
#pragma unroll
  for (int ds = 0; ds < 4; ds++)
#pragma unroll
    for (int rg = 0; rg < 4; rg++) {
      f32x4 v;
#pragma unroll
      for (int i = 0; i < 4; i++) v[i] = yacc[ds][rg * 4 + i] * invl;
      *(f32x4*)(orow + ds * 32 + rg * 8 + hi5 * 4) = v;
    }
}

extern "C" void kernel_launch(void* const* d_in, const int* in_sizes, int n_in,
                              void* d_out, int out_size, void* d_ws, size_t ws_size,
                              hipStream_t stream) {
  const float* x  = (const float*)d_in[0];
  const float* wq = (const float*)d_in[1];
  const float* qb = (const float*)d_in[2];
  const float* wk = (const float*)d_in[3];
  const float* kb = (const float*)d_in[4];
  const float* wv = (const float*)d_in[5];
  const float* vb = (const float*)d_in[6];
  const float* rh = (const float*)d_in[7];
  const float* rw = (const float*)d_in[8];
  float* out = (float*)d_out;
  char* ws = (char*)d_ws;
  // ws layout (bytes): xt 16,777,216 | wb 1,572,864 | Q 16,777,216 | K 16,777,216 | V 16,777,216
  unsigned short* xt = (unsigned short*)(ws);
  unsigned short* wb = (unsigned short*)(ws + 16777216);
  unsigned short* Q  = (unsigned short*)(ws + 18350080);
  unsigned short* K  = (unsigned short*)(ws + 35127296);
  unsigned short* V  = (unsigned short*)(ws + 51904512);
  k_prep<<<2304, 256, 0, stream>>>(x, xt, wq, wk, wv, wb);
  k_qkv<<<1536, 256, 0, stream>>>(wb, xt, qb, kb, vb, rh, rw, Q, K, V);
  k_attn<<<512, 256, 0, stream>>>(Q, K, V, out);
}

// Round 18
// 101.198 us; speedup vs baseline: 1.0351x; 1.0013x over previous
//
#include <hip/hip_runtime.h>
#include <hip/hip_bf16.h>
#include <cstdint>

#define NB 16
#define NC 512
#define NPIX 1024
#define NHEADS 4
#define NEMB 128

typedef short bf16x8 __attribute__((ext_vector_type(8)));
typedef float f32x4 __attribute__((ext_vector_type(4)));
typedef float f32x16 __attribute__((ext_vector_type(16)));
typedef unsigned short u16x4 __attribute__((ext_vector_type(4)));
typedef unsigned short u16x8 __attribute__((ext_vector_type(8)));

__device__ __forceinline__ unsigned short f2bf(float f) {
  union { float f; unsigned u; } c; c.f = f;
  return (unsigned short)((c.u + 0x7FFFu + ((c.u >> 16) & 1u)) >> 16);
}

__device__ __forceinline__ unsigned cvtpk_bf16(float lo, float hi) {
  unsigned r;
  asm("v_cvt_pk_bf16_f32 %0, %1, %2" : "=v"(r) : "v"(lo), "v"(hi));
  return r;
}

__device__ __forceinline__ void gload_lds16(const void* g, void* l) {
  __builtin_amdgcn_global_load_lds(
      (const __attribute__((address_space(1))) unsigned int*)g,
      (__attribute__((address_space(3))) unsigned int*)l, 16, 0, 0);
}

// ---------- merged prep: blocks 0..2047 transpose x -> xt; 2048..2303 convert w ----------
__global__ void k_prep(const float* __restrict__ x, unsigned short* __restrict__ xt,
                       const float* __restrict__ wq, const float* __restrict__ wk,
                       const float* __restrict__ wv, unsigned short* __restrict__ wb) {
  int bid = blockIdx.x;
  if (bid >= 2048) {
    int wbid = bid - 2048;
    for (int i = wbid * 256 + threadIdx.x; i < 3 * 65536; i += 256 * 256) {
      int p = i >> 16, idx = i & 65535;
      const float* src = p == 0 ? wq : (p == 1 ? wk : wv);
      float4 v = ((const float4*)src)[idx];
      u16x4 o = { f2bf(v.x), f2bf(v.y), f2bf(v.z), f2bf(v.w) };
      ((u16x4*)(wb + (size_t)p * NC * NC))[idx] = o;
    }
    return;
  }
  __shared__ float tile[4][32][33];
  int nt = bid & 31, ct4 = (bid >> 5) & 3, b = bid >> 7;
  int n0 = nt * 32, c0 = ct4 * 128;
  int t = threadIdx.x;
  int r = t >> 3, q = t & 7;
#pragma unroll
  for (int s = 0; s < 4; s++) {
    float4 v = *(const float4*)(x + ((size_t)(b * NC + c0 + s * 32 + r)) * NPIX + n0 + q * 4);
    tile[s][r][q * 4 + 0] = v.x; tile[s][r][q * 4 + 1] = v.y;
    tile[s][r][q * 4 + 2] = v.z; tile[s][r][q * 4 + 3] = v.w;
  }
  __syncthreads();
#pragma unroll
  for (int pass = 0; pass < 2; pass++) {
    int idx = pass * 256 + t;
    int n = idx >> 4;
    int c8 = (idx & 15) * 8;
    int s = c8 >> 5, cl = c8 & 31;
    u16x8 o;
#pragma unroll
    for (int j = 0; j < 8; j++) o[j] = f2bf(tile[s][cl + j][n]);
    *(u16x8*)(xt + ((size_t)(b * NPIX + n0 + n)) * NC + c0 + c8) = o;
  }
}

// ---------- QKV projection GEMM (r14: LDS-restaged coalesced epilogue) ----------
// p==0: Q -> (acc+bias)*scale*log2e, [b][hd][n][e]  (exp2-domain)
// p==1: K -> acc+bias+rh+rw, tiles 16KB: elem(jl,e) at byte jl*256 + ((2e)^((jl&7)<<4))
// p==2: V -> acc+bias,       tiles 16KB: elem(d,jl) at byte d*128 + ((2jl)^((d&7)<<4))
__global__ __launch_bounds__(256, 3) void k_qkv(
    const unsigned short* __restrict__ wb, const unsigned short* __restrict__ xt,
    const float* __restrict__ qb, const float* __restrict__ kb, const float* __restrict__ vb,
    const float* __restrict__ rh, const float* __restrict__ rw,
    unsigned short* __restrict__ Qs, unsigned short* __restrict__ Kn,
    unsigned short* __restrict__ Vm) {
  __shared__ __align__(16) char smem[32768];
  unsigned short* Alds = (unsigned short*)smem;
  unsigned short* Blds = (unsigned short*)(smem + 16384);
  int bid = blockIdx.x;
  int nt = bid & 7, mt = (bid >> 3) & 3;
  int rest = bid >> 5;
  int p = rest % 3, b = rest / 3;
  int m0 = mt * 128, n0 = nt * 128;
  const unsigned short* A = wb + (size_t)p * NC * NC + (size_t)m0 * NC;
  const unsigned short* Bx = xt + (size_t)b * NPIX * NC + (size_t)n0 * NC;
  int t = threadIdx.x;
  int lane = t & 63, wid = t >> 6;
  int wm = (wid >> 1) * 64, wn = (wid & 1) * 64;
  f32x4 acc[4][4] = {};
  for (int k0 = 0; k0 < NC; k0 += 64) {
#pragma unroll
    for (int i = 0; i < 4; i++) {
      int idx = i * 256 + t;
      int row = idx >> 3, col = (idx & 7) * 8;
      gload_lds16(A + (size_t)row * NC + k0 + col, &Alds[idx * 8]);
    }
#pragma unroll
    for (int i = 0; i < 4; i++) {
      int idx = i * 256 + t;
      int row = idx >> 3, col = (idx & 7) * 8;
      gload_lds16(Bx + (size_t)row * NC + k0 + col, &Blds[idx * 8]);
    }
    __syncthreads();
#pragma unroll
    for (int ks = 0; ks < 2; ks++) {
      int kk = ks * 32 + ((lane >> 4) << 3);
      bf16x8 af[4], bfr[4];
#pragma unroll
      for (int f = 0; f < 4; f++)
        af[f] = *(const bf16x8*)&Alds[(wm + f * 16 + (lane & 15)) * 64 + kk];
#pragma unroll
      for (int f = 0; f < 4; f++)
        bfr[f] = *(const bf16x8*)&Blds[(wn + f * 16 + (lane & 15)) * 64 + kk];
#pragma unroll
      for (int fm = 0; fm < 4; fm++)
#pragma unroll
        for (int fn = 0; fn < 4; fn++)
          acc[fm][fn] = __builtin_amdgcn_mfma_f32_16x16x32_bf16(af[fm], bfr[fn], acc[fm][fn], 0, 0, 0);
    }
    __syncthreads();  // last iter: all LDS reads done -> safe to reuse smem below
  }
  // 512^-0.5 * log2(e): softmax runs in exp2 domain
  const float scale = 0.044194173824159216f * 1.4426950408889634f;
  // ---- build final-layout 32KB tile in LDS ----
  if (p == 2) {
#pragma unroll
    for (int fm = 0; fm < 4; fm++) {
#pragma unroll
      for (int r = 0; r < 4; r++) {
        int d = wm + fm * 16 + ((lane >> 4) << 2) + r;
        float bv = vb[m0 + d];
#pragma unroll
        for (int fn = 0; fn < 4; fn++) {
          int jloc = wn + fn * 16 + (lane & 15);
          int sub = jloc >> 6, jl = jloc & 63;
          *(unsigned short*)(smem + sub * 16384 + d * 128 + ((2 * jl) ^ ((d & 7) << 4))) =
              f2bf(acc[fm][fn][r] + bv);
        }
      }
    }
  } else if (p == 1) {
#pragma unroll
    for (int fm = 0; fm < 4; fm++) {
      int e0 = wm + fm * 16 + ((lane >> 4) << 2);
#pragma unroll
      for (int fn = 0; fn < 4; fn++) {
        int jloc = wn + fn * 16 + (lane & 15);
        int jg = n0 + jloc;
        int sub = jloc >> 6, jl = jloc & 63;
        u16x4 o;
#pragma unroll
        for (int r = 0; r < 4; r++) {
          float v = acc[fm][fn][r] + kb[m0 + e0 + r];
          v += rh[(m0 + e0 + r) * 32 + (jg & 31)] + rw[(m0 + e0 + r) * 32 + (jg >> 5)];
          o[r] = f2bf(v);
        }
        *(u16x4*)(smem + sub * 16384 + jl * 256 + ((2 * e0) ^ ((jl & 7) << 4))) = o;
      }
    }
  } else {
#pragma unroll
    for (int fm = 0; fm < 4; fm++) {
      int e0 = wm + fm * 16 + ((lane >> 4) << 2);
#pragma unroll
      for (int fn = 0; fn < 4; fn++) {
        int ncol = wn + fn * 16 + (lane & 15);
        u16x4 o;
#pragma unroll
        for (int r = 0; r < 4; r++)
          o[r] = f2bf((acc[fm][fn][r] + qb[m0 + e0 + r]) * scale);
        *(u16x4*)(smem + ncol * 256 + 2 * e0) = o;
      }
    }
  }
  __syncthreads();
  // ---- coalesced copy-out: 8 x 16B per thread ----
  char* gdst;
  if (p == 0)
    gdst = (char*)(Qs + ((size_t)((b * NHEADS + mt) * NPIX + n0)) * NEMB);
  else if (p == 1)
    gdst = (char*)(Kn + (size_t)(b * NHEADS + mt) * 131072 + (size_t)(n0 >> 6) * 8192);
  else
    gdst = (char*)(Vm + (size_t)(b * NHEADS + mt) * 131072 + (size_t)(n0 >> 6) * 8192);
#pragma unroll
  for (int i = 0; i < 8; i++)
    *(u16x8*)(gdst + i * 4096 + t * 16) = *(const u16x8*)(smem + i * 4096 + t * 16);
}

// ---------- flash attention v15: r17 chunk pipeline + cross-tile chunk1 deferral ----------
// Tiles 1..14: chunk1's exp2/pack/PV23 of tile t-1 executes inside tile t's chain0
// window (S-chunk1 and V-chunks-2,3 are register-resident, so the LDS buffer swap
// doesn't invalidate them). Statically-named A/B ping-pong (rule #20), tiles 0/15
// peeled. Identical arithmetic to r17 — pure cross-tile reorder.
__global__ __launch_bounds__(256, 2) void k_attn(
    const unsigned short* __restrict__ Qs, const unsigned short* __restrict__ Kp,
    const unsigned short* __restrict__ Vp, float* __restrict__ out) {
  __shared__ __align__(16) char smem[65536];  // K dbuf 2x16KB @0, V dbuf 2x16KB @32768
  int bid = blockIdx.x;
  int pair = bid & 63;
  int b = pair >> 2, hd = pair & 3;
  int i0 = (bid >> 6) * 128;
  int t = threadIdx.x, w = t >> 6, lane = t & 63;
  int l31 = lane & 31, hi5 = lane >> 5;
  const unsigned short* Qb = Qs + (size_t)pair * NPIX * NEMB;
  const char* Kpb = (const char*)(Kp + (size_t)pair * 131072);
  const char* Vpb = (const char*)(Vp + (size_t)pair * 131072);
  const int swz = (l31 & 7) << 4;

  bf16x8 qf[8];
  {
    const unsigned short* qr = Qb + (size_t)(i0 + w * 32 + l31) * NEMB + hi5 * 8;
#pragma unroll
    for (int d8 = 0; d8 < 8; d8++) qf[d8] = *(const bf16x8*)(qr + d8 * 16);
  }
  f32x16 yacc[4] = {};
  float l = 0.f;

  // prologue: stage tile 0 into buf 0
#pragma unroll
  for (int r = 0; r < 4; r++) {
    gload_lds16(Kpb + r * 4096 + t * 16, smem + r * 4096 + t * 16);
    gload_lds16(Vpb + r * 4096 + t * 16, smem + 32768 + r * 4096 + t * 16);
  }
  __syncthreads();

  // helper pieces (macros keep register names static)
#define PREFETCH(nt_, slot_)                                                    \
  {                                                                             \
    const char* kn = Kpb + (nt_) * 16384;                                       \
    const char* vn = Vpb + (nt_) * 16384;                                       \
    char* kd = smem + (slot_) * 16384;                                          \
    char* vd = smem + 32768 + (slot_) * 16384;                                  \
    _Pragma("unroll") for (int r = 0; r < 4; r++) {                             \
      gload_lds16(kn + r * 4096 + t * 16, kd + r * 4096 + t * 16);              \
      gload_lds16(vn + r * 4096 + t * 16, vd + r * 4096 + t * 16);              \
    }                                                                           \
  }

#define CHAIN(S_, Kl_, roff_)                                                   \
  _Pragma("unroll") for (int d8 = 0; d8 < 8; d8++) {                            \
    int colb = (d8 * 32 + hi5 * 16) ^ swz;                                      \
    bf16x8 kf = *(const bf16x8*)((Kl_) + (roff_ + l31) * 256 + colb);           \
    S_ = __builtin_amdgcn_mfma_f32_32x32x16_bf16(kf, qf[d8], S_, 0, 0, 0);      \
  }

#define EXP_PACK_PV(S_, V_, rsum_)                                              \
  {                                                                             \
    _Pragma("unroll") for (int i = 0; i < 16; i += 4) {                         \
      float p0 = exp2f(S_[i + 0]);                                              \
      float p1 = exp2f(S_[i + 1]);                                              \
      float p2 = exp2f(S_[i + 2]);                                              \
      float p3 = exp2f(S_[i + 3]);                                              \
      S_[i + 0] = p0; S_[i + 1] = p1; S_[i + 2] = p2; S_[i + 3] = p3;           \
      rsum_ += (p0 + p1) + (p2 + p3);                                           \
    }                                                                           \
    unsigned uu[4][2];                                                          \
    _Pragma("unroll") for (int g = 0; g < 4; g++) {                             \
      uu[g][0] = cvtpk_bf16(S_[4 * g + 0], S_[4 * g + 1]);                      \
      uu[g][1] = cvtpk_bf16(S_[4 * g + 2], S_[4 * g + 3]);                      \
    }                                                                           \
    _Pragma("unroll") for (int c2 = 0; c2 < 2; c2++) {                          \
      int gA = c2 * 2, gB = gA + 1;                                             \
      unsigned a0 = uu[gA][0], b0 = uu[gB][0];                                  \
      unsigned a1 = uu[gA][1], b1 = uu[gB][1];                                  \
      asm("v_permlane32_swap_b32 %0, %1" : "+v"(a0), "+v"(b0));                 \
      asm("v_permlane32_swap_b32 %0, %1" : "+v"(a1), "+v"(b1));                 \
      unsigned wd[4] = { a0, a1, b0, b1 };                                      \
      bf16x8 pfx = *(bf16x8*)wd;                                                \
      _Pragma("unroll") for (int ds = 0; ds < 4; ds++)                          \
        yacc[ds] = __builtin_amdgcn_mfma_f32_32x32x16_bf16(V_[c2][ds], pfx,     \
                                                           yacc[ds], 0, 0, 0); \
    }                                                                           \
  }

#define VLOAD(V_, Vl_, cbase_)                                                  \
  _Pragma("unroll") for (int c2 = 0; c2 < 2; c2++) {                            \
    int colb = ((cbase_ + c2) * 32 + hi5 * 16) ^ swz;                           \
    _Pragma("unroll") for (int ds = 0; ds < 4; ds++)                            \
      V_[c2][ds] = *(const bf16x8*)((Vl_) + (ds * 32 + l31) * 128 + colb);      \
  }

  f32x16 sA, sB;
  bf16x8 vAx[2][4], vBx[2][4];
  float rsum = 0.f;

  // ---- tile 0 (peeled): produce (sA, vAx) ----
  {
    PREFETCH(1, 1);
    const char* Kl = smem;
    const char* Vl = smem + 32768;
    f32x16 s0 = (f32x16)(0.0f);
    CHAIN(s0, Kl, 0);
    bf16x8 vloc[2][4];
    VLOAD(vloc, Vl, 0);
    VLOAD(vAx, Vl, 2);
    sA = (f32x16)(0.0f);
    CHAIN(sA, Kl, 32);
    EXP_PACK_PV(s0, vloc, rsum);
    __syncthreads();
  }

  // one pipelined tile: consumes (sin, vin), produces (sout, vout)
#define BODY(tt_, sin_, vin_, sout_, vout_, pre_)                               \
  {                                                                             \
    if (pre_) PREFETCH((tt_) + 1, ((tt_) & 1) ^ 1);                             \
    const char* Kl = smem + ((tt_) & 1) * 16384;                                \
    const char* Vl = smem + 32768 + ((tt_) & 1) * 16384;                        \
    f32x16 s0 = (f32x16)(0.0f);                                                 \
    CHAIN(s0, Kl, 0);                                                           \
    EXP_PACK_PV(sin_, vin_, rsum);  /* deferred chunk1 of tile tt_-1 */         \
    bf16x8 vloc[2][4];                                                          \
    VLOAD(vloc, Vl, 0);                                                         \
    VLOAD(vout_, Vl, 2);                                                        \
    sout_ = (f32x16)(0.0f);                                                     \
    CHAIN(sout_, Kl, 32);                                                       \
    EXP_PACK_PV(s0, vloc, rsum);                                                \
    __syncthreads();                                                            \
  }

  // ---- tiles 1..14 (A/B ping-pong, statically named) ----
#pragma unroll
  for (int i = 0; i < 7; i++) {
    BODY(1 + 2 * i, sA, vAx, sB, vBx, true);
    BODY(2 + 2 * i, sB, vBx, sA, vAx, true);
  }
  // ---- tile 15 (peeled): consume (sA, vAx), produce (sB, vBx), no prefetch/barrier ----
  {
    const char* Kl = smem + 16384;
    const char* Vl = smem + 32768 + 16384;
    f32x16 s0 = (f32x16)(0.0f);
    CHAIN(s0, Kl, 0);
    EXP_PACK_PV(sA, vAx, rsum);
    bf16x8 vloc[2][4];
    VLOAD(vloc, Vl, 0);
    VLOAD(vBx, Vl, 2);
    sB = (f32x16)(0.0f);
    CHAIN(sB, Kl, 32);
    EXP_PACK_PV(s0, vloc, rsum);
    // final deferred chunk
    EXP_PACK_PV(sB, vBx, rsum);
  }
  l = rsum;

  // epilogue: combine l across halves once; q = i0+w*32+l31 per lane;
  // d = ds*32 + rg*8 + hi5*4 + (0..3)
  float ltot = l + __shfl_xor(l, 32);
  float invl = 1.0f / ltot;
  int q = i0 + w * 32 + l31;
  float* orow = out + ((size_t)(b * NC + hd * NEMB + (q >> 3))) * NPIX + (q & 7) * NEMB;
#pragma unroll
  for (int ds = 0; ds < 4; ds++)
#pragma unroll
    for (int rg = 0; rg < 4; rg++) {
      f32x4 v;
#pragma unroll
      for (int i = 0; i < 4; i++) v[i] = yacc[ds][rg * 4 + i] * invl;
      *(f32x4*)(orow + ds * 32 + rg * 8 + hi5 * 4) = v;
    }
#undef PREFETCH
#undef CHAIN
#undef EXP_PACK_PV
#undef VLOAD
#undef BODY
}

extern "C" void kernel_launch(void* const* d_in, const int* in_sizes, int n_in,
                              void* d_out, int out_size, void* d_ws, size_t ws_size,
                              hipStream_t stream) {
  const float* x  = (const float*)d_in[0];
  const float* wq = (const float*)d_in[1];
  const float* qb = (const float*)d_in[2];
  const float* wk = (const float*)d_in[3];
  const float* kb = (const float*)d_in[4];
  const float* wv = (const float*)d_in[5];
  const float* vb = (const float*)d_in[6];
  const float* rh = (const float*)d_in[7];
  const float* rw = (const float*)d_in[8];
  float* out = (float*)d_out;
  char* ws = (char*)d_ws;
  // ws layout (bytes): xt 16,777,216 | wb 1,572,864 | Q 16,777,216 | K 16,777,216 | V 16,777,216
  unsigned short* xt = (unsigned short*)(ws);
  unsigned short* wb = (unsigned short*)(ws + 16777216);
  unsigned short* Q  = (unsigned short*)(ws + 18350080);
  unsigned short* K  = (unsigned short*)(ws + 35127296);
  unsigned short* V  = (unsigned short*)(ws + 51904512);
  k_prep<<<2304, 256, 0, stream>>>(x, xt, wq, wk, wv, wb);
  k_qkv<<<1536, 256, 0, stream>>>(wb, xt, qb, kb, vb, rh, rw, Q, K, V);
  k_attn<<<512, 256, 0, stream>>>(Q, K, V, out);
}